// Round 1
// 128.183 us; speedup vs baseline: 1.1081x; 1.1081x over previous
//
#include <hip/hip_runtime.h>
#include <hip/hip_bf16.h>

#define B_ 8
#define N_ 512

typedef __attribute__((ext_vector_type(8))) __bf16 bf16x8;
typedef __attribute__((ext_vector_type(8))) _Float16 f16x8;
typedef __attribute__((ext_vector_type(4))) _Float16 f16x4;
typedef __attribute__((ext_vector_type(2))) _Float16 h2;
typedef __attribute__((ext_vector_type(4))) float f32x4;
typedef __attribute__((ext_vector_type(4))) unsigned int u32x4;
typedef __attribute__((ext_vector_type(2))) unsigned int u32x2;

// pack two fp32 into bf16x2 by truncation: 1 v_perm_b32
__device__ __forceinline__ unsigned pk_bf16(float hi, float lo) {
    return __builtin_amdgcn_perm(__builtin_bit_cast(unsigned, hi),
                                 __builtin_bit_cast(unsigned, lo), 0x07060302u);
}

__device__ __forceinline__ h2 pkrtz(float a, float b) {
    return __builtin_bit_cast(h2, __builtin_amdgcn_cvt_pkrtz(a, b));
}
__device__ __forceinline__ unsigned pkrtz_u(float a, float b) {
    return __builtin_bit_cast(unsigned, __builtin_amdgcn_cvt_pkrtz(a, b));
}
// relu (pk_max_f16 vs 0) on a packed pair, returned as dword
__device__ __forceinline__ unsigned relu2_u(h2 v) {
    const h2 z2 = {(_Float16)0.0f, (_Float16)0.0f};
    return __builtin_bit_cast(unsigned, __builtin_elementwise_max(v, z2));
}

// ---------------- mega kernel: adj (MFMA-everything) | node MLP | prep | zero
// [0,2048)     adjacency MLP: L0 via row-permuted mfma 16x16x16f16,
//              L1 via mfma 16x16x32_f16, L2 reduction via mfma 16x16x16f16.
// [2048,3072)  node MLP, 4 rows/block
// [3072,3328)  w0t transpose (coalesced reads)
// [3328,3456)  w1t transpose
// [3456,3460)  zero d_out
__global__ __launch_bounds__(256) void k_mega(
    const float* __restrict__ coords,
    const float* __restrict__ fw0, const float* __restrict__ fb0,
    const float* __restrict__ fw1, const float* __restrict__ fb1,
    const float* __restrict__ aw0, const float* __restrict__ ab0,
    const float* __restrict__ aw1, const float* __restrict__ ab1,
    const float* __restrict__ aw2, const float* __restrict__ ab2,
    const float* __restrict__ uw0, const float* __restrict__ uw1,
    __bf16* __restrict__ h_bf, __bf16* __restrict__ h_t,
    __bf16* __restrict__ w0t, __bf16* __restrict__ w1t,
    __bf16* __restrict__ A,
    float* __restrict__ out, int out_size)
{
    const int blk = blockIdx.x;
    const int t = threadIdx.x;

    if (blk < 2048) {
        // ================= adjacency MLP =================
        __shared__ __align__(16) _Float16 s_aw1p[4096];
        __shared__ float s_eb[64];
        __shared__ __align__(8) unsigned s_cj[256][2];

        const int b = blk >> 8;
        const int half = blk & 1;

        // ---- inline prep: aw1 fragments (f16) + epilogue bias + packed cj --
        {
            const int base = t * 16;
            _Float16 bt[16];
#pragma unroll
            for (int e = 0; e < 16; ++e) {
                int id = base + e;
                int j = id & 7, mm = (id >> 3) & 15, qq = (id >> 7) & 3;
                int ct = (id >> 9) & 3, s = (id >> 11) & 1;
                bt[e] = (_Float16)aw1[(s * 32 + qq * 8 + j) * 64 + ct * 16 + mm];
            }
            *(f16x8*)&s_aw1p[base] = *(f16x8*)&bt[0];
            *(f16x8*)&s_aw1p[base + 8] = *(f16x8*)&bt[8];
            if (t < 64) {
                int qq = t >> 4, ct = (t >> 2) & 3, r = t & 3;
                s_eb[t] = ab1[ct * 16 + qq * 4 + r];
            }
            // cj for this half, packed f16 {c0,c1,c2,1}
            const float* cj = coords + (size_t)(b * N_ + half * 256 + t) * 3;
            s_cj[t][0] = pkrtz_u(cj[0], cj[1]);
            s_cj[t][1] = pkrtz_u(cj[2], 1.0f);
        }
        __syncthreads();

        const int l = t & 63;
        const int wave = t >> 6;
        const int q = l >> 4;
        const int m = l & 15;
        const int i = (((blk >> 1) & 127) << 2) + wave;

        const float* ci = coords + (size_t)(b * N_ + i) * 3;
        const float ci0 = ci[0], ci1 = ci[1], ci2 = ci[2];

        // ---- layer-0 A-fragments: rows permuted so D == layer-1 B layout.
        // MFMA t4 row m -> ch = (m>>2)*8 + (m&3) + {0,4,32,36}[t4].
        // k=0..2: aw0 rows 3..5 (cj part); k=3: o_i (bias + ci part) folded.
        f16x4 a0f[4];
        {
            const int chb = ((m >> 2) << 3) + (m & 3);
            const int offs[4] = {0, 4, 32, 36};
#pragma unroll
            for (int t4 = 0; t4 < 4; ++t4) {
                const int ch = chb + offs[t4];
                float w3 = aw0[192 + ch], w4 = aw0[256 + ch], w5 = aw0[320 + ch];
                float o = ab0[ch] + ci0 * aw0[ch] + ci1 * aw0[64 + ch]
                                  + ci2 * aw0[128 + ch];
                u32x2 fr;
                fr[0] = (q == 0) ? pkrtz_u(w3, w4) : 0u;
                fr[1] = (q == 0) ? pkrtz_u(w5, o) : 0u;
                a0f[t4] = __builtin_bit_cast(f16x4, fr);
            }
        }

        // ---- layer-2 reduction A-fragments: k=q*4+e -> ch=ct*16+q*4+e,
        // broadcast over rows (every D row equals the reduced scalar).
        f16x4 ewf[4];
#pragma unroll
        for (int ct = 0; ct < 4; ++ct) {
            const float* ep = aw2 + ct * 16 + (q << 2);
            u32x2 fr;
            fr[0] = pkrtz_u(ep[0], ep[1]);
            fr[1] = pkrtz_u(ep[2], ep[3]);
            ewf[ct] = __builtin_bit_cast(f16x4, fr);
        }

        f16x8 bfr[2][4];
#pragma unroll
        for (int s = 0; s < 2; ++s)
#pragma unroll
            for (int ct = 0; ct < 4; ++ct)
                bfr[s][ct] = *(const f16x8*)&s_aw1p[s * 2048 + ct * 512 + q * 128 + m * 8];

        f32x4 ab1q[4];
#pragma unroll
        for (int ct = 0; ct < 4; ++ct)
            ab1q[ct] = *(const f32x4*)&s_eb[q * 16 + ct * 4];

        const float ab2s = ab2[0];
        const f32x4 pr0 = {ab2s, ab2s, ab2s, ab2s};
        const f32x4 zf = {0.f, 0.f, 0.f, 0.f};

        __bf16* Arow = A + ((size_t)(b * N_ + i) << 9) + half * 256;

#pragma unroll 1
        for (int tt = 0; tt < 16; ++tt) {
            f16x4 bj = __builtin_bit_cast(f16x4, *(const u32x2*)s_cj[(tt << 4) + m]);

            // layer 0: 4 row-permuted MFMAs (K=16, k=0..3 live)
            f32x4 d0 = __builtin_amdgcn_mfma_f32_16x16x16f16(a0f[0], bj, zf, 0, 0, 0);
            f32x4 d1 = __builtin_amdgcn_mfma_f32_16x16x16f16(a0f[1], bj, zf, 0, 0, 0);
            f32x4 d2 = __builtin_amdgcn_mfma_f32_16x16x16f16(a0f[2], bj, zf, 0, 0, 0);
            f32x4 d3 = __builtin_amdgcn_mfma_f32_16x16x16f16(a0f[3], bj, zf, 0, 0, 0);

            // relu + pack straight into layer-1 B-fragments
            u32x4 pa, pb;
            pa[0] = relu2_u(pkrtz(d0[0], d0[1]));
            pa[1] = relu2_u(pkrtz(d0[2], d0[3]));
            pa[2] = relu2_u(pkrtz(d1[0], d1[1]));
            pa[3] = relu2_u(pkrtz(d1[2], d1[3]));
            pb[0] = relu2_u(pkrtz(d2[0], d2[1]));
            pb[1] = relu2_u(pkrtz(d2[2], d2[3]));
            pb[2] = relu2_u(pkrtz(d3[0], d3[1]));
            pb[3] = relu2_u(pkrtz(d3[2], d3[3]));
            f16x8 a0 = __builtin_bit_cast(f16x8, pa);
            f16x8 a1 = __builtin_bit_cast(f16x8, pb);

            // layer 1 transposed MFMA (f16); ab1 folded into C (D != C, no copies)
            f32x4 c0v = __builtin_amdgcn_mfma_f32_16x16x32_f16(bfr[0][0], a0, ab1q[0], 0, 0, 0);
            c0v = __builtin_amdgcn_mfma_f32_16x16x32_f16(bfr[1][0], a1, c0v, 0, 0, 0);
            f32x4 c1v = __builtin_amdgcn_mfma_f32_16x16x32_f16(bfr[0][1], a0, ab1q[1], 0, 0, 0);
            c1v = __builtin_amdgcn_mfma_f32_16x16x32_f16(bfr[1][1], a1, c1v, 0, 0, 0);
            f32x4 c2v = __builtin_amdgcn_mfma_f32_16x16x32_f16(bfr[0][2], a0, ab1q[2], 0, 0, 0);
            c2v = __builtin_amdgcn_mfma_f32_16x16x32_f16(bfr[1][2], a1, c2v, 0, 0, 0);
            f32x4 c3v = __builtin_amdgcn_mfma_f32_16x16x32_f16(bfr[0][3], a0, ab1q[3], 0, 0, 0);
            c3v = __builtin_amdgcn_mfma_f32_16x16x32_f16(bfr[1][3], a1, c3v, 0, 0, 0);

            // layer 2: relu + pack, then reduce over 64 chs via 4 chained MFMAs
            u32x2 r0, r1, r2, r3;
            r0[0] = relu2_u(pkrtz(c0v[0], c0v[1]));
            r0[1] = relu2_u(pkrtz(c0v[2], c0v[3]));
            r1[0] = relu2_u(pkrtz(c1v[0], c1v[1]));
            r1[1] = relu2_u(pkrtz(c1v[2], c1v[3]));
            r2[0] = relu2_u(pkrtz(c2v[0], c2v[1]));
            r2[1] = relu2_u(pkrtz(c2v[2], c2v[3]));
            r3[0] = relu2_u(pkrtz(c3v[0], c3v[1]));
            r3[1] = relu2_u(pkrtz(c3v[2], c3v[3]));

            f32x4 pr = __builtin_amdgcn_mfma_f32_16x16x16f16(
                ewf[0], __builtin_bit_cast(f16x4, r0), pr0, 0, 0, 0);
            pr = __builtin_amdgcn_mfma_f32_16x16x16f16(
                ewf[1], __builtin_bit_cast(f16x4, r1), pr, 0, 0, 0);
            pr = __builtin_amdgcn_mfma_f32_16x16x16f16(
                ewf[2], __builtin_bit_cast(f16x4, r2), pr, 0, 0, 0);
            pr = __builtin_amdgcn_mfma_f32_16x16x16f16(
                ewf[3], __builtin_bit_cast(f16x4, r3), pr, 0, 0, 0);

            if (l < 16) Arow[(tt << 4) + l] = (__bf16)fmaxf(pr[0], 0.0f);
        }
    } else if (blk < 3072) {
        // ================= node MLP: 4 rows/block =================
        const int row0 = (blk - 2048) << 2;
        const int b = row0 >> 9;
        const int n0 = row0 & 511;
        __shared__ float cds4[4][4];
        __shared__ float hid4[4][64];
        if (t < 12) {
            int r = t / 3, d = t - 3 * r;
            cds4[r][d] = coords[(size_t)row0 * 3 + t];
        }
        __syncthreads();
        {
            int r = t >> 6, ch = t & 63;
            float v = fb0[ch];
            v += cds4[r][0] * fw0[0 * 64 + ch];
            v += cds4[r][1] * fw0[1 * 64 + ch];
            v += cds4[r][2] * fw0[2 * 64 + ch];
            hid4[r][ch] = fmaxf(v, 0.0f);
        }
        __syncthreads();
        {
            int ch = t & 127;
            int rp = (t >> 7) << 1;          // rows rp, rp+1
            float hv0 = fb1[ch], hv1 = hv0;
#pragma unroll 4
            for (int k = 0; k < 64; ++k) {
                float w = fw1[k * 128 + ch];
                hv0 += hid4[rp][k] * w;
                hv1 += hid4[rp + 1][k] * w;
            }
            hv0 = fmaxf(hv0, 0.0f);
            hv1 = fmaxf(hv1, 0.0f);
            h_bf[((size_t)(row0 + rp) << 7) + ch] = (__bf16)hv0;
            h_bf[((size_t)(row0 + rp + 1) << 7) + ch] = (__bf16)hv1;
            *(unsigned*)(h_t + (size_t)(b * 128 + ch) * 512 + n0 + rp) =
                pk_bf16(hv1, hv0);
        }
    } else if (blk < 3328) {
        // ---- w0t[c][k] = uw0[perm(k)][c]; coalesced read ----
        int k = blk - 3072;
        int c = t;
        int src = (k < 128) ? k : (k + 3);
        w0t[(size_t)c * 256 + k] = (__bf16)uw0[(size_t)src * 256 + c];
    } else if (blk < 3456) {
        // ---- w1t[c][k] = uw1[k][c]; coalesced read ----
        int id = (blk - 3328) * 256 + t;
        int c = id & 127, k = id >> 7;
        w1t[(size_t)c * 256 + k] = (__bf16)uw1[(size_t)k * 128 + c];
    } else {
        int i = (blk - 3456) * 256 + t;
        if (i < out_size) out[i] = 0.0f;
    }
}

// ---------------- fused  V = A@h (MFMA, K-split x2)  +  update MLP ----------
// 256 blocks x 1024 thr (16 waves). act/u1 rows padded 256->264 bf16 to break
// the 512B-stride 16-way LDS bank conflict on A-fragment ds_read_b128.
__global__ __launch_bounds__(1024) void k_aggupd(
    const __bf16* __restrict__ A, const __bf16* __restrict__ h_t,
    const __bf16* __restrict__ h_bf, const float* __restrict__ coords,
    const float* __restrict__ uw0, const float* __restrict__ ub0,
    const __bf16* __restrict__ w0t, const __bf16* __restrict__ w1t,
    const float* __restrict__ ub1,
    float* __restrict__ out)
{
    const int t = threadIdx.x;
    const int w = t >> 6;            // wave 0..15
    const int gw = w & 7;            // n-tile
    const int ks = w >> 3;           // K-half
    const int l = t & 63;
    const int q = l >> 4;
    const int m = l & 15;
    const int row0 = blockIdx.x << 4;   // 16 GLOBAL rows, same b
    const int b = row0 >> 9;

    __shared__ __align__(16) __bf16 act[16][264];  // [row][k], k=[h|V], padded
    __shared__ __align__(16) __bf16 u1[16][264];
    __shared__ float vp[2][16][128];
    __shared__ float cds[16][4];

    // stage h part of act: 1024 thr x 4B covers 16x128 bf16
    {
        unsigned hv = *(const unsigned*)(h_bf + ((size_t)row0 << 7) + t * 2);
        *(unsigned*)&act[(t * 2) >> 7][(t * 2) & 127] = hv;
    }
    if (t < 48) {
        int r = t / 3, d = t - 3 * r;
        cds[r][d] = coords[(size_t)row0 * 3 + t];
    }

    // ---- aggregate: V n-tile gw, K-half ks (A indexed by global row) ----
    const __bf16* Ar = A + (size_t)(row0 + m) * 512 + ks * 256 + q * 8;
    const __bf16* hp = h_t + ((size_t)b << 16) + (size_t)(gw * 16 + m) * 512
                       + ks * 256 + q * 8;
    f32x4 acc = {0.f, 0.f, 0.f, 0.f};
#pragma unroll 4
    for (int kt = 0; kt < 8; ++kt) {
        bf16x8 av = *(const bf16x8*)(Ar + kt * 32);
        bf16x8 bv = *(const bf16x8*)(hp + kt * 32);
        acc = __builtin_amdgcn_mfma_f32_16x16x32_bf16(av, bv, acc, 0, 0, 0);
    }
#pragma unroll
    for (int r = 0; r < 4; ++r)
        vp[ks][q * 4 + r][gw * 16 + m] = acc[r];
    __syncthreads();

    // combine K-halves -> act V part (1024 thr x 2 values)
#pragma unroll
    for (int it = 0; it < 2; ++it) {
        int idx = t + it * 1024;
        int row = idx >> 7, ch = idx & 127;
        act[row][128 + ch] = (__bf16)(vp[0][row][ch] + vp[1][row][ch]);
    }
    __syncthreads();

    // ---- layer 1: col c = w*16 + m (16 waves cover 256 cols) ----
    bf16x8 af[8];
#pragma unroll
    for (int ch = 0; ch < 8; ++ch)
        af[ch] = *(const bf16x8*)&act[m][q * 8 + 32 * ch];
    {
        const int c = w * 16 + m;
        const float wx = uw0[128 * 256 + c];
        const float wy = uw0[129 * 256 + c];
        const float wz = uw0[130 * 256 + c];
        const float bias = ub0[c];
        f32x4 a1c;
#pragma unroll
        for (int r = 0; r < 4; ++r)
            a1c[r] = bias + cds[q * 4 + r][0] * wx + cds[q * 4 + r][1] * wy
                          + cds[q * 4 + r][2] * wz;
        const __bf16* wp = w0t + (size_t)c * 256 + q * 8;
#pragma unroll
        for (int ch = 0; ch < 8; ++ch) {
            bf16x8 bfr = *(const bf16x8*)(wp + 32 * ch);
            a1c = __builtin_amdgcn_mfma_f32_16x16x32_bf16(af[ch], bfr, a1c, 0, 0, 0);
        }
#pragma unroll
        for (int r = 0; r < 4; ++r)
            u1[q * 4 + r][c] = (__bf16)fmaxf(a1c[r], 0.0f);
    }
    __syncthreads();

    // ---- layer 2: cols w*16 + m on waves 0..7 ----
    if (w < 8) {
        bf16x8 af2[8];
#pragma unroll
        for (int ch = 0; ch < 8; ++ch)
            af2[ch] = *(const bf16x8*)&u1[m][q * 8 + 32 * ch];
        const int c = w * 16 + m;
        float bias = ub1[c];
        f32x4 a2c = {bias, bias, bias, bias};
        const __bf16* wp = w1t + (size_t)c * 256 + q * 8;
#pragma unroll
        for (int ch = 0; ch < 8; ++ch) {
            bf16x8 bfr = *(const bf16x8*)(wp + 32 * ch);
            a2c = __builtin_amdgcn_mfma_f32_16x16x32_bf16(af2[ch], bfr, a2c, 0, 0, 0);
        }
        float mx = fmaxf(fmaxf(a2c[0], a2c[1]), fmaxf(a2c[2], a2c[3]));
        mx = fmaxf(mx, 0.0f);
        mx = fmaxf(mx, __shfl_xor(mx, 16, 64));
        mx = fmaxf(mx, __shfl_xor(mx, 32, 64));
        if (l < 16)
            atomicMax((int*)(out + ((size_t)b << 7) + c), __float_as_int(mx));
    }
}

extern "C" void kernel_launch(void* const* d_in, const int* in_sizes, int n_in,
                              void* d_out, int out_size, void* d_ws, size_t ws_size,
                              hipStream_t stream)
{
    const float* coords = (const float*)d_in[0];
    const float* fw0 = (const float*)d_in[1];
    const float* fb0 = (const float*)d_in[2];
    const float* fw1 = (const float*)d_in[3];
    const float* fb1 = (const float*)d_in[4];
    const float* aw0 = (const float*)d_in[5];
    const float* ab0 = (const float*)d_in[6];
    const float* aw1 = (const float*)d_in[7];
    const float* ab1 = (const float*)d_in[8];
    const float* aw2 = (const float*)d_in[9];
    const float* ab2 = (const float*)d_in[10];
    const float* uw0 = (const float*)d_in[11];
    const float* ub0 = (const float*)d_in[12];
    const float* uw1 = (const float*)d_in[13];
    const float* ub1 = (const float*)d_in[14];
    float* out = (float*)d_out;

    // workspace layout
    char* ws = (char*)d_ws;
    __bf16* A    = (__bf16*)(ws);                            // 4 MB
    __bf16* h_t  = (__bf16*)(ws + (4u << 20));               // 1 MB
    __bf16* h_bf = (__bf16*)(ws + (5u << 20));               // 1 MB
    __bf16* w0t  = (__bf16*)(ws + (6u << 20));               // 128 KB
    __bf16* w1t  = (__bf16*)(ws + (6u << 20) + (128u << 10));// 64 KB

    k_mega<<<3460, 256, 0, stream>>>(coords, fw0, fb0, fw1, fb1,
                                     aw0, ab0, aw1, ab1, aw2, ab2, uw0, uw1,
                                     h_bf, h_t, w0t, w1t, A, out, out_size);
    k_aggupd<<<256, 1024, 0, stream>>>(A, h_t, h_bf, coords, uw0, ub0,
                                       w0t, w1t, ub1, out);
}